// Round 1
// baseline (136.861 us; speedup 1.0000x reference)
//
#include <hip/hip_runtime.h>
#include <math.h>

// QuantumPolicy: MLP(6->64->6) -> 6-qubit RY/CNOT circuit (4 layers) -> Z exp
// -> softmax policy head (4) + value head (1).
//
// LANE-SPLIT version: each sample is handled by a LANE PAIR (DPP quad
// neighbors). Qubit 0 lives on the thread-lane parity bit; qubits 1..4 live in
// the per-lane register index j (bit 4-i); qubit 5 is the v2 component. Each
// lane holds 32 amplitudes (16 x float2). This doubles the wave count
// (4 -> 8 waves/SIMD) so in-phase stalls (scalar weight loads, sincos chains,
// i-fetch) are hidden by out-of-phase waves -- the prior kernel sat at
// VALUBusy ~30% with only 4 waves/SIMD resident.
//
// Cross-lane ops use v_mov_dpp quad_perm[1,0,3,2] (full-rate VALU, no LDS):
//   - CNOT(5,0): swap .y across the lane pair          (16 dpp / layer)
//   - CNOT(0,1): parity-controlled j<->j|8 swap        (cndmask, 32 / layer)
//   - RY(q0):    direct rotation vs. partner amplitude (32 dpp + 32 pk / layer)
// Other CNOTs stay compile-time register renames; RY(q1..q4) stay packed
// 3-shear (tan/sin decomposition, range-reduced); RY(q5) scalar shears.
//
// MLP is computed redundantly on both lanes of a pair (keeps weight loads
// scalar/uniform), with MLP2 FUSED into MLP1 so h[64] never materializes:
// peak live state ~56-64 VGPRs -> __launch_bounds__(256,8) grants 8 waves/SIMD.

#define NQ 6
#define NL 4
#define NA 4
#define PD 64

typedef float v2 __attribute__((ext_vector_type(2)));

__device__ __forceinline__ v2 mk2(float a, float b) { v2 r; r.x = a; r.y = b; return r; }
__device__ __forceinline__ v2 pkfma(v2 a, v2 b, v2 c) { return __builtin_elementwise_fma(a, b, c); }

// Swap with DPP-quad neighbor (lane ^ 1). Full-rate VALU, exec all-on.
__device__ __forceinline__ float dppx1(float v) {
    int i = __builtin_bit_cast(int, v);
    i = __builtin_amdgcn_mov_dpp(i, 0xB1, 0xF, 0xF, true); // quad_perm [1,0,3,2]
    return __builtin_bit_cast(float, i);
}

__global__ __launch_bounds__(256, 8) void qpolicy_kernel(
    const float* __restrict__ x,
    const float* __restrict__ W1,
    const float* __restrict__ b1,
    const float* __restrict__ W2,
    const float* __restrict__ b2,
    const float* __restrict__ qw,
    const float* __restrict__ Wp,
    const float* __restrict__ bp,
    const float* __restrict__ Wv,
    const float* __restrict__ bv,
    float* __restrict__ out,
    int B)
{
    const int t = blockIdx.x * blockDim.x + threadIdx.x; // 0 .. 2B-1
    const int s = t >> 1;                                // sample index
    const bool podd = (t & 1) != 0;                      // q0 value of this lane

    // ---- load x[s, 0:6] as 3 x float2 (both lanes of a pair load the same
    // 24 B; L1 broadcast).
    const v2* xv = reinterpret_cast<const v2*>(x + (size_t)s * NQ);
    const v2 x01 = xv[0], x23 = xv[1], x45 = xv[2];

    const v2* W1v = reinterpret_cast<const v2*>(W1);  // rows of 6 = 3 v2
    const v2* W2v = reinterpret_cast<const v2*>(W2);  // rows of 64 = 32 v2

    // ---- fused MLP: xp = relu(relu(x@W1^T+b1)@W2^T+b2), h never materialized.
    v2 xpa[NQ];
#pragma unroll
    for (int i = 0; i < NQ; ++i) xpa[i] = mk2(b2[i], 0.0f);
#pragma unroll
    for (int k2 = 0; k2 < PD / 2; ++k2) {
        float hu[2];
#pragma unroll
        for (int u = 0; u < 2; ++u) {
            const int j = 2 * k2 + u;
            v2 acc = mk2(b1[j], 0.0f);
            acc = pkfma(x01, W1v[j * 3 + 0], acc);
            acc = pkfma(x23, W1v[j * 3 + 1], acc);
            acc = pkfma(x45, W1v[j * 3 + 2], acc);
            hu[u] = fmaxf(acc.x + acc.y, 0.0f);
        }
        const v2 hv = mk2(hu[0], hu[1]);
#pragma unroll
        for (int i = 0; i < NQ; ++i)
            xpa[i] = pkfma(hv, W2v[i * (PD / 2) + k2], xpa[i]);
    }
    float xp[NQ];
#pragma unroll
    for (int i = 0; i < NQ; ++i) xp[i] = fmaxf(xpa[i].x + xpa[i].y, 0.0f);

    // ---- AngleEmbedding: product state. q0 factor is lane-parity select;
    // pr[16] spans q1..q4 (q_i at j-bit 4-i); q5 in the v2 components.
    float cq[NQ], sq[NQ];
#pragma unroll
    for (int q = 0; q < NQ; ++q) __sincosf(0.5f * xp[q], &sq[q], &cq[q]);

    const float g0 = podd ? sq[0] : cq[0];
    float pr[16];
    pr[0] = g0;
#pragma unroll
    for (int q = 1; q <= 4; ++q) {
        const int sz = 1 << (q - 1);
#pragma unroll
        for (int k = sz - 1; k >= 0; --k) {
            const float v = pr[k];
            pr[2 * k]     = v * cq[q];
            pr[2 * k + 1] = v * sq[q];
        }
    }
    v2 st[16];
    const v2 cs5 = mk2(cq[5], sq[5]);
#pragma unroll
    for (int j = 0; j < 16; ++j) st[j] = mk2(pr[j], pr[j]) * cs5;

    // ---- 4 layers of [CNOT ring] + [RY(qw[l,i])]
#pragma unroll
    for (int l = 0; l < NL; ++l) {
        // CNOT(0,1): ctrl = lane parity (q0), tgt = j-bit3 (q1).
#pragma unroll
        for (int j = 0; j < 8; ++j) {
            const v2 a = st[j], b = st[j | 8];
            st[j]     = podd ? b : a;
            st[j | 8] = podd ? a : b;
        }
        // CNOT(1,2), (2,3), (3,4): pure register renames.
#pragma unroll
        for (int j = 0; j < 16; ++j)
            if ((j & 8) && !(j & 4)) { v2 tmp = st[j]; st[j] = st[j | 4]; st[j | 4] = tmp; }
#pragma unroll
        for (int j = 0; j < 16; ++j)
            if ((j & 4) && !(j & 2)) { v2 tmp = st[j]; st[j] = st[j | 2]; st[j | 2] = tmp; }
#pragma unroll
        for (int j = 0; j < 16; ++j)
            if ((j & 2) && !(j & 1)) { v2 tmp = st[j]; st[j] = st[j | 1]; st[j | 1] = tmp; }
        // CNOT(4,5): ctrl = j-bit0 (q4), tgt = v2 component swap.
#pragma unroll
        for (int j = 0; j < 16; ++j)
            if (j & 1) st[j] = __builtin_shufflevector(st[j], st[j], 1, 0);
        // CNOT(5,0): ctrl = .y (q5), tgt = lane parity -> swap .y across pair.
#pragma unroll
        for (int j = 0; j < 16; ++j) st[j].y = dppx1(st[j].y);

        // Per-layer rotation constants. q0 uses the direct (c,s) rotation;
        // q1..q5 use tan-shears with range reduction (global sign killed by
        // the final squaring).
        float s0r, c0r;
        __sincosf(0.5f * qw[l * NQ + 0], &s0r, &c0r);
        const float ssg = podd ? s0r : -s0r;  // new_p = c*mine + ssg*other
        float tv[NQ], sv[NQ];
#pragma unroll
        for (int i = 1; i < NQ; ++i) {
            float hh = 0.5f * qw[l * NQ + i];
            hh = (hh > 1.5707963f) ? (hh - 3.14159265358979f) : hh;
            float sh, ch;
            __sincosf(hh, &sh, &ch);
            sv[i] = sh;
            tv[i] = sh * __builtin_amdgcn_rcpf(1.0f + ch);  // stable: 1+ch in [1,2]
        }

        // RY(q0): cross-lane direct rotation via DPP partner fetch.
        {
            const v2 c2 = mk2(c0r, c0r), sg2 = mk2(ssg, ssg);
#pragma unroll
            for (int j = 0; j < 16; ++j) {
                v2 o;
                o.x = dppx1(st[j].x);
                o.y = dppx1(st[j].y);
                st[j] = pkfma(sg2, o, st[j] * c2);
            }
        }
        // RY(q1..q4): 3 packed shears per register pair (8 pairs each).
#pragma unroll
        for (int i = 1; i <= 4; ++i) {
            const int m = 1 << (4 - i);
            const v2 vnt = mk2(-tv[i], -tv[i]);
            const v2 vs  = mk2(sv[i], sv[i]);
#pragma unroll
            for (int j = 0; j < 16; ++j) {
                if (!(j & m)) {
                    v2 a = st[j], b = st[j | m];
                    a = pkfma(vnt, b, a);
                    b = pkfma(vs, a, b);
                    a = pkfma(vnt, b, a);
                    st[j] = a; st[j | m] = b;
                }
            }
        }
        // RY(q5): intra-register scalar shears.
        {
            const float nt = -tv[5], s5 = sv[5];
#pragma unroll
            for (int j = 0; j < 16; ++j) {
                float a0 = st[j].x, a1 = st[j].y;
                a0 = fmaf(nt, a1, a0);
                a1 = fmaf(s5, a0, a1);
                a0 = fmaf(nt, a1, a0);
                st[j] = mk2(a0, a1);
            }
        }
    }

    // ---- probabilities + Z expectations. Per-lane partial tree over the 32
    // local amps, then one DPP add per sum to fold in the partner half.
    float a[16];
    float S5l = 0.0f;
#pragma unroll
    for (int j = 0; j < 16; ++j) {
        const v2 pp = st[j] * st[j];
        a[j] = pp.x + pp.y;
        S5l += pp.x;
    }
    float S1l = 0.0f;
#pragma unroll
    for (int j = 0; j < 8; ++j) S1l += a[j];
    float b8[8];
#pragma unroll
    for (int j = 0; j < 8; ++j) b8[j] = a[j] + a[j | 8];
    const float S2l = b8[0] + b8[1] + b8[2] + b8[3];
    float b4[4];
#pragma unroll
    for (int j = 0; j < 4; ++j) b4[j] = b8[j] + b8[j | 4];
    const float S3l = b4[0] + b4[1];
    float b2v[2];
    b2v[0] = b4[0] + b4[2];
    b2v[1] = b4[1] + b4[3];
    const float S4l = b2v[0];
    const float Tl  = b2v[0] + b2v[1];

    const float To = dppx1(Tl);
    const float T  = Tl + To;
    const float S0 = podd ? To : Tl;           // total prob of the q0=0 lane
    const float S1 = S1l + dppx1(S1l);
    const float S2 = S2l + dppx1(S2l);
    const float S3 = S3l + dppx1(S3l);
    const float S4 = S4l + dppx1(S4l);
    const float S5 = S5l + dppx1(S5l);

    float z[NQ];
    z[0] = fmaf(2.0f, S0, -T);
    z[1] = fmaf(2.0f, S1, -T);
    z[2] = fmaf(2.0f, S2, -T);
    z[3] = fmaf(2.0f, S3, -T);
    z[4] = fmaf(2.0f, S4, -T);
    z[5] = fmaf(2.0f, S5, -T);

    // ---- heads (computed on both lanes, stored by the even lane only).
    float logits[NA];
#pragma unroll
    for (int aidx = 0; aidx < NA; ++aidx) {
        float acc = bp[aidx];
#pragma unroll
        for (int q = 0; q < NQ; ++q) acc = fmaf(z[q], Wp[aidx * NQ + q], acc);
        logits[aidx] = acc;
    }
    float m = logits[0];
#pragma unroll
    for (int aidx = 1; aidx < NA; ++aidx) m = fmaxf(m, logits[aidx]);
    float e[NA];
    float esum = 0.0f;
#pragma unroll
    for (int aidx = 0; aidx < NA; ++aidx) { e[aidx] = __expf(logits[aidx] - m); esum += e[aidx]; }
    const float inv = 1.0f / esum;

    float4 pol;
    pol.x = e[0] * inv; pol.y = e[1] * inv; pol.z = e[2] * inv; pol.w = e[3] * inv;

    float v = bv[0];
#pragma unroll
    for (int q = 0; q < NQ; ++q) v = fmaf(z[q], Wv[q], v);

    if (!podd) {
        reinterpret_cast<float4*>(out)[s] = pol;       // policy: (B,4)
        out[(size_t)B * NA + s] = v;                   // value: (B,)
    }
}

extern "C" void kernel_launch(void* const* d_in, const int* in_sizes, int n_in,
                              void* d_out, int out_size, void* d_ws, size_t ws_size,
                              hipStream_t stream) {
    const float* x  = (const float*)d_in[0];
    const float* W1 = (const float*)d_in[1];
    const float* b1 = (const float*)d_in[2];
    const float* W2 = (const float*)d_in[3];
    const float* b2 = (const float*)d_in[4];
    const float* qw = (const float*)d_in[5];
    const float* Wp = (const float*)d_in[6];
    const float* bp = (const float*)d_in[7];
    const float* Wv = (const float*)d_in[8];
    const float* bv = (const float*)d_in[9];
    float* out = (float*)d_out;

    const int B = in_sizes[0] / NQ;      // 262144
    dim3 block(256);
    dim3 grid((2 * B + 255) / 256);      // two lanes per sample
    hipLaunchKernelGGL(qpolicy_kernel, grid, block, 0, stream,
                       x, W1, b1, W2, b2, qw, Wp, bp, Wv, bv, out, B);
}

// Round 2
// 113.077 us; speedup vs baseline: 1.2103x; 1.2103x over previous
//
#include <hip/hip_runtime.h>
#include <math.h>

// QuantumPolicy: MLP(6->64->6) -> 6-qubit RY/CNOT circuit (4 layers) -> Z exp
// -> softmax policy head (4) + value head (1).
//
// LANE-SPLIT version: each sample is handled by a LANE PAIR (DPP quad
// neighbors). Qubit 0 lives on the thread-lane parity bit; qubits 1..4 live in
// the per-lane register index j (bit 4-i); qubit 5 is the v2 component. Each
// lane holds 32 amplitudes (16 x float2). This doubles the wave count vs the
// one-thread-per-sample version (grid 8192 waves -> can fill all 8 wave
// slots/SIMD), hiding in-phase stalls (scalar weight loads, sincos chains).
//
// ROUND-2 FIX: round 1's __launch_bounds__(256,8) forced a 32-VGPR budget ->
// ~95 MB/dispatch scratch spill traffic (FETCH 33.5 MB / WRITE 64.5 MB) which
// exactly cancelled the occupancy win. Plain __launch_bounds__(256) lets the
// allocator land at its natural ~48 regs (state = 32) -- still under the
// 64-reg occupancy cliff, no spill.
//
// Also: CNOT(5,0) is FUSED into RY(q0)'s partner fetch. The standalone .y
// lane-swap followed by a partner fetch composes to pure component routing:
//   new = c*(x, dpp(y)) + ssg*(dpp(x), y)
// which deletes 16 DPP movs/layer.
//
// Cross-lane ops are v_mov_dpp quad_perm[1,0,3,2] (full-rate VALU, no LDS).
// Other CNOTs are compile-time register renames; RY(q1..q4) are packed
// 3-shear (tan/sin decomposition, range-reduced); RY(q5) scalar shears.
// MLP is computed redundantly on both lanes of a pair (keeps weight loads
// scalar/uniform), with MLP2 fused into MLP1 so h[64] never materializes.

#define NQ 6
#define NL 4
#define NA 4
#define PD 64

typedef float v2 __attribute__((ext_vector_type(2)));

__device__ __forceinline__ v2 mk2(float a, float b) { v2 r; r.x = a; r.y = b; return r; }
__device__ __forceinline__ v2 pkfma(v2 a, v2 b, v2 c) { return __builtin_elementwise_fma(a, b, c); }

// Swap with DPP-quad neighbor (lane ^ 1). Full-rate VALU, exec all-on.
__device__ __forceinline__ float dppx1(float v) {
    int i = __builtin_bit_cast(int, v);
    i = __builtin_amdgcn_mov_dpp(i, 0xB1, 0xF, 0xF, true); // quad_perm [1,0,3,2]
    return __builtin_bit_cast(float, i);
}

__global__ __launch_bounds__(256) void qpolicy_kernel(
    const float* __restrict__ x,
    const float* __restrict__ W1,
    const float* __restrict__ b1,
    const float* __restrict__ W2,
    const float* __restrict__ b2,
    const float* __restrict__ qw,
    const float* __restrict__ Wp,
    const float* __restrict__ bp,
    const float* __restrict__ Wv,
    const float* __restrict__ bv,
    float* __restrict__ out,
    int B)
{
    const int t = blockIdx.x * blockDim.x + threadIdx.x; // 0 .. 2B-1
    const int s = t >> 1;                                // sample index
    const bool podd = (t & 1) != 0;                      // q0 value of this lane

    // ---- load x[s, 0:6] as 3 x float2 (both lanes of a pair load the same
    // 24 B; L1 broadcast).
    const v2* xv = reinterpret_cast<const v2*>(x + (size_t)s * NQ);
    const v2 x01 = xv[0], x23 = xv[1], x45 = xv[2];

    const v2* W1v = reinterpret_cast<const v2*>(W1);  // rows of 6 = 3 v2
    const v2* W2v = reinterpret_cast<const v2*>(W2);  // rows of 64 = 32 v2

    // ---- fused MLP: xp = relu(relu(x@W1^T+b1)@W2^T+b2), h never materialized.
    v2 xpa[NQ];
#pragma unroll
    for (int i = 0; i < NQ; ++i) xpa[i] = mk2(b2[i], 0.0f);
#pragma unroll
    for (int k2 = 0; k2 < PD / 2; ++k2) {
        float hu[2];
#pragma unroll
        for (int u = 0; u < 2; ++u) {
            const int j = 2 * k2 + u;
            v2 acc = mk2(b1[j], 0.0f);
            acc = pkfma(x01, W1v[j * 3 + 0], acc);
            acc = pkfma(x23, W1v[j * 3 + 1], acc);
            acc = pkfma(x45, W1v[j * 3 + 2], acc);
            hu[u] = fmaxf(acc.x + acc.y, 0.0f);
        }
        const v2 hv = mk2(hu[0], hu[1]);
#pragma unroll
        for (int i = 0; i < NQ; ++i)
            xpa[i] = pkfma(hv, W2v[i * (PD / 2) + k2], xpa[i]);
    }
    float xp[NQ];
#pragma unroll
    for (int i = 0; i < NQ; ++i) xp[i] = fmaxf(xpa[i].x + xpa[i].y, 0.0f);

    // ---- AngleEmbedding: product state. q0 factor is lane-parity select;
    // pr[16] spans q1..q4 (q_i at j-bit 4-i); q5 in the v2 components.
    float cq[NQ], sq[NQ];
#pragma unroll
    for (int q = 0; q < NQ; ++q) __sincosf(0.5f * xp[q], &sq[q], &cq[q]);

    const float g0 = podd ? sq[0] : cq[0];
    float pr[16];
    pr[0] = g0;
#pragma unroll
    for (int q = 1; q <= 4; ++q) {
        const int sz = 1 << (q - 1);
#pragma unroll
        for (int k = sz - 1; k >= 0; --k) {
            const float v = pr[k];
            pr[2 * k]     = v * cq[q];
            pr[2 * k + 1] = v * sq[q];
        }
    }
    v2 st[16];
    const v2 cs5 = mk2(cq[5], sq[5]);
#pragma unroll
    for (int j = 0; j < 16; ++j) st[j] = mk2(pr[j], pr[j]) * cs5;

    // ---- 4 layers of [CNOT ring] + [RY(qw[l,i])]
#pragma unroll
    for (int l = 0; l < NL; ++l) {
        // CNOT(0,1): ctrl = lane parity (q0), tgt = j-bit3 (q1).
#pragma unroll
        for (int j = 0; j < 8; ++j) {
            const v2 a = st[j], b = st[j | 8];
            st[j]     = podd ? b : a;
            st[j | 8] = podd ? a : b;
        }
        // CNOT(1,2), (2,3), (3,4): pure register renames.
#pragma unroll
        for (int j = 0; j < 16; ++j)
            if ((j & 8) && !(j & 4)) { v2 tmp = st[j]; st[j] = st[j | 4]; st[j | 4] = tmp; }
#pragma unroll
        for (int j = 0; j < 16; ++j)
            if ((j & 4) && !(j & 2)) { v2 tmp = st[j]; st[j] = st[j | 2]; st[j | 2] = tmp; }
#pragma unroll
        for (int j = 0; j < 16; ++j)
            if ((j & 2) && !(j & 1)) { v2 tmp = st[j]; st[j] = st[j | 1]; st[j | 1] = tmp; }
        // CNOT(4,5): ctrl = j-bit0 (q4), tgt = v2 component swap.
#pragma unroll
        for (int j = 0; j < 16; ++j)
            if (j & 1) st[j] = __builtin_shufflevector(st[j], st[j], 1, 0);

        // Per-layer rotation constants. q0 uses the direct (c,s) rotation;
        // q1..q5 use tan-shears with range reduction (global sign killed by
        // the final squaring).
        float s0r, c0r;
        __sincosf(0.5f * qw[l * NQ + 0], &s0r, &c0r);
        const float ssg = podd ? s0r : -s0r;  // new_p = c*mine + ssg*other
        float tv[NQ], sv[NQ];
#pragma unroll
        for (int i = 1; i < NQ; ++i) {
            float hh = 0.5f * qw[l * NQ + i];
            hh = (hh > 1.5707963f) ? (hh - 3.14159265358979f) : hh;
            float sh, ch;
            __sincosf(hh, &sh, &ch);
            sv[i] = sh;
            tv[i] = sh * __builtin_amdgcn_rcpf(1.0f + ch);  // stable: 1+ch in [1,2]
        }

        // CNOT(5,0) fused with RY(q0). Standalone form:
        //   st' = (st.x, dpp(st.y));  new = c*st' + ssg*dpp(st')
        // composes to pure component routing (dpp is an involution):
        //   new = c*(st.x, dpp(st.y)) + ssg*(dpp(st.x), st.y)
        {
            const v2 c2 = mk2(c0r, c0r), sg2 = mk2(ssg, ssg);
#pragma unroll
            for (int j = 0; j < 16; ++j) {
                const float px = dppx1(st[j].x);
                const float py = dppx1(st[j].y);
                const v2 A = mk2(st[j].x, py);   // own.x, partner(post-CNOT).y
                const v2 Bv = mk2(px, st[j].y);  // partner.x, own(post-CNOT).y
                st[j] = pkfma(sg2, Bv, A * c2);
            }
        }
        // RY(q1..q4): 3 packed shears per register pair (8 pairs each).
#pragma unroll
        for (int i = 1; i <= 4; ++i) {
            const int m = 1 << (4 - i);
            const v2 vnt = mk2(-tv[i], -tv[i]);
            const v2 vs  = mk2(sv[i], sv[i]);
#pragma unroll
            for (int j = 0; j < 16; ++j) {
                if (!(j & m)) {
                    v2 a = st[j], b = st[j | m];
                    a = pkfma(vnt, b, a);
                    b = pkfma(vs, a, b);
                    a = pkfma(vnt, b, a);
                    st[j] = a; st[j | m] = b;
                }
            }
        }
        // RY(q5): intra-register scalar shears.
        {
            const float nt = -tv[5], s5 = sv[5];
#pragma unroll
            for (int j = 0; j < 16; ++j) {
                float a0 = st[j].x, a1 = st[j].y;
                a0 = fmaf(nt, a1, a0);
                a1 = fmaf(s5, a0, a1);
                a0 = fmaf(nt, a1, a0);
                st[j] = mk2(a0, a1);
            }
        }
    }

    // ---- probabilities + Z expectations. Per-lane partial tree over the 32
    // local amps, then one DPP add per sum to fold in the partner half.
    float a[16];
    float S5l = 0.0f;
#pragma unroll
    for (int j = 0; j < 16; ++j) {
        const v2 pp = st[j] * st[j];
        a[j] = pp.x + pp.y;
        S5l += pp.x;
    }
    float S1l = 0.0f;
#pragma unroll
    for (int j = 0; j < 8; ++j) S1l += a[j];
    float b8[8];
#pragma unroll
    for (int j = 0; j < 8; ++j) b8[j] = a[j] + a[j | 8];
    const float S2l = b8[0] + b8[1] + b8[2] + b8[3];
    float b4[4];
#pragma unroll
    for (int j = 0; j < 4; ++j) b4[j] = b8[j] + b8[j | 4];
    const float S3l = b4[0] + b4[1];
    float b2v[2];
    b2v[0] = b4[0] + b4[2];
    b2v[1] = b4[1] + b4[3];
    const float S4l = b2v[0];
    const float Tl  = b2v[0] + b2v[1];

    const float To = dppx1(Tl);
    const float T  = Tl + To;
    const float S0 = podd ? To : Tl;           // total prob of the q0=0 lane
    const float S1 = S1l + dppx1(S1l);
    const float S2 = S2l + dppx1(S2l);
    const float S3 = S3l + dppx1(S3l);
    const float S4 = S4l + dppx1(S4l);
    const float S5 = S5l + dppx1(S5l);

    float z[NQ];
    z[0] = fmaf(2.0f, S0, -T);
    z[1] = fmaf(2.0f, S1, -T);
    z[2] = fmaf(2.0f, S2, -T);
    z[3] = fmaf(2.0f, S3, -T);
    z[4] = fmaf(2.0f, S4, -T);
    z[5] = fmaf(2.0f, S5, -T);

    // ---- heads (computed on both lanes, stored by the even lane only).
    float logits[NA];
#pragma unroll
    for (int aidx = 0; aidx < NA; ++aidx) {
        float acc = bp[aidx];
#pragma unroll
        for (int q = 0; q < NQ; ++q) acc = fmaf(z[q], Wp[aidx * NQ + q], acc);
        logits[aidx] = acc;
    }
    float m = logits[0];
#pragma unroll
    for (int aidx = 1; aidx < NA; ++aidx) m = fmaxf(m, logits[aidx]);
    float e[NA];
    float esum = 0.0f;
#pragma unroll
    for (int aidx = 0; aidx < NA; ++aidx) { e[aidx] = __expf(logits[aidx] - m); esum += e[aidx]; }
    const float inv = 1.0f / esum;

    float4 pol;
    pol.x = e[0] * inv; pol.y = e[1] * inv; pol.z = e[2] * inv; pol.w = e[3] * inv;

    float v = bv[0];
#pragma unroll
    for (int q = 0; q < NQ; ++q) v = fmaf(z[q], Wv[q], v);

    if (!podd) {
        reinterpret_cast<float4*>(out)[s] = pol;       // policy: (B,4)
        out[(size_t)B * NA + s] = v;                   // value: (B,)
    }
}

extern "C" void kernel_launch(void* const* d_in, const int* in_sizes, int n_in,
                              void* d_out, int out_size, void* d_ws, size_t ws_size,
                              hipStream_t stream) {
    const float* x  = (const float*)d_in[0];
    const float* W1 = (const float*)d_in[1];
    const float* b1 = (const float*)d_in[2];
    const float* W2 = (const float*)d_in[3];
    const float* b2 = (const float*)d_in[4];
    const float* qw = (const float*)d_in[5];
    const float* Wp = (const float*)d_in[6];
    const float* bp = (const float*)d_in[7];
    const float* Wv = (const float*)d_in[8];
    const float* bv = (const float*)d_in[9];
    float* out = (float*)d_out;

    const int B = in_sizes[0] / NQ;      // 262144
    dim3 block(256);
    dim3 grid((2 * B + 255) / 256);      // two lanes per sample
    hipLaunchKernelGGL(qpolicy_kernel, grid, block, 0, stream,
                       x, W1, b1, W2, b2, qw, Wp, bp, Wv, bv, out, B);
}

// Round 3
// 106.253 us; speedup vs baseline: 1.2881x; 1.0642x over previous
//
#include <hip/hip_runtime.h>
#include <math.h>

// QuantumPolicy: MLP(6->64->6) -> 6-qubit RY/CNOT circuit (4 layers) -> Z exp
// -> softmax policy head (4) + value head (1).
//
// LANE-SPLIT (round 2, kept): each sample is handled by a DPP lane pair.
// Qubit 0 = lane parity; qubits 1..4 = register index bits; qubit 5 = v2
// component. 16 x float2 state per lane; 8 waves/SIMD resident.
//
// ROUND-3: move all wave-uniform work into a 1-block PREP KERNEL writing d_ws:
//  (a) layer rotation constants pre-computed (range-reduced (-t, s) shear form,
//      (c, s) for qubit 0) -> zero transcendentals in the main circuit loop
//      (was ~17 trans + ~30 VALU per layer per thread, all in-phase bursts);
//  (b) W1/b1/W2 repacked into per-iteration 128 B streaming blocks
//      [W1 col-pairs x6 | b1 pair | W2 pairs x6], 64 B aligned -> the MLP's
//      ~13 scattered s_loads/iter become 2 wide s_load_dwordx16, and the
//      column-pair layout yields the ReLU'd hidden PAIR directly in one
//      v_pk_max_f32 (no horizontal add, no repack): 13 pk-inst/iter vs ~17.
// Also: block-phase stagger via s_sleep to decorrelate the 8 resident
// waves/SIMD (they otherwise hit scalar-cache / trans bursts in lockstep).
//
// ws layout (floats): [0..63] layer consts (16/layer: c0,s0,nt1,s1..nt5,s5),
//                     [64..1087] 32 MLP blocks x 32 floats.

#define NQ 6
#define NL 4
#define NA 4
#define PD 64

typedef float v2 __attribute__((ext_vector_type(2)));

__device__ __forceinline__ v2 mk2(float a, float b) { v2 r; r.x = a; r.y = b; return r; }
__device__ __forceinline__ v2 pkfma(v2 a, v2 b, v2 c) { return __builtin_elementwise_fma(a, b, c); }

// Swap with DPP-quad neighbor (lane ^ 1). Full-rate VALU, exec all-on.
__device__ __forceinline__ float dppx1(float v) {
    int i = __builtin_bit_cast(int, v);
    i = __builtin_amdgcn_mov_dpp(i, 0xB1, 0xF, 0xF, true); // quad_perm [1,0,3,2]
    return __builtin_bit_cast(float, i);
}

// ---- prep kernel: 1 block x 256. Runs once per dispatch sequence (~2-3 us).
__global__ void qprep_kernel(const float* __restrict__ W1,
                             const float* __restrict__ b1,
                             const float* __restrict__ W2,
                             const float* __restrict__ qw,
                             float* __restrict__ ws)
{
    const int t = threadIdx.x;
    // layer rotation constants
    if (t < NL * NQ) {
        const int l = t / NQ, i = t % NQ;
        const float hh0 = 0.5f * qw[l * NQ + i];
        float* dst = ws + l * 16;
        if (i == 0) {
            dst[0] = cosf(hh0);
            dst[1] = sinf(hh0);
        } else {
            // range-reduce into (-pi/2, pi/2]; global sign killed by squaring
            const float hh = (hh0 > 1.5707963f) ? (hh0 - 3.14159265358979f) : hh0;
            const float sh = sinf(hh), ch = cosf(hh);
            dst[2 * i]     = -sh / (1.0f + ch);   // -tan(h/2), |t| <= 1
            dst[2 * i + 1] = sh;
        }
    }
    // MLP streaming blocks: 32 blocks x 32 floats
    for (int idx = t; idx < 32 * 32; idx += 256) {
        const int k2 = idx >> 5, e = idx & 31;
        float v = 0.0f;
        if (e < 12) {                       // W1 column pairs: q = e>>1, u = e&1
            const int q = e >> 1, u = e & 1;
            v = W1[(2 * k2 + u) * NQ + q];
        } else if (e < 14) {                // b1 pair
            v = b1[2 * k2 + (e - 12)];
        } else if (e < 26) {                // W2 pairs: i = (e-14)>>1, u = e&1
            const int i2 = (e - 14) >> 1, u = e & 1;
            v = W2[i2 * PD + 2 * k2 + u];
        }
        ws[64 + idx] = v;
    }
}

__global__ __launch_bounds__(256) void qpolicy_kernel(
    const float* __restrict__ x,
    const float* __restrict__ b2,
    const float* __restrict__ Wp,
    const float* __restrict__ bp,
    const float* __restrict__ Wv,
    const float* __restrict__ bv,
    const float* __restrict__ ws,
    float* __restrict__ out,
    int B)
{
    // stagger resident blocks so the 8 waves/SIMD don't hit scalar-load /
    // store phases in lockstep (<= ~3.5k cycles = 1.5 us worst-case skew)
    const int ph = blockIdx.x & 7;
#pragma unroll 1
    for (int i = 0; i < ph; ++i) __builtin_amdgcn_s_sleep(8);

    const int t = blockIdx.x * blockDim.x + threadIdx.x; // 0 .. 2B-1
    const int s = t >> 1;                                // sample index
    const bool podd = (t & 1) != 0;                      // q0 value of this lane

    // ---- load x[s, 0:6] as 3 x float2 (pair lanes share 24 B; L1 broadcast)
    const v2* xv = reinterpret_cast<const v2*>(x + (size_t)s * NQ);
    const v2 x01 = xv[0], x23 = xv[1], x45 = xv[2];

    // broadcast x components into both halves for packed column-pair FMA
    v2 xb[NQ];
    xb[0] = mk2(x01.x, x01.x); xb[1] = mk2(x01.y, x01.y);
    xb[2] = mk2(x23.x, x23.x); xb[3] = mk2(x23.y, x23.y);
    xb[4] = mk2(x45.x, x45.x); xb[5] = mk2(x45.y, x45.y);

    // ---- fused MLP over streaming blocks: per k2, one ReLU'd hidden PAIR.
    const v2* __restrict__ wblk = reinterpret_cast<const v2*>(ws + 64);
    const v2 zero2 = mk2(0.0f, 0.0f);
    v2 xpa[NQ];
#pragma unroll
    for (int i = 0; i < NQ; ++i) xpa[i] = mk2(b2[i], 0.0f);
#pragma unroll
    for (int k2 = 0; k2 < PD / 2; ++k2) {
        const v2* blk = wblk + k2 * 16;
        v2 acc = blk[6];                                  // (b1[2k2], b1[2k2+1])
#pragma unroll
        for (int q = 0; q < NQ; ++q) acc = pkfma(xb[q], blk[q], acc);
        const v2 hv = __builtin_elementwise_max(acc, zero2);  // ReLU'd pair
#pragma unroll
        for (int i = 0; i < NQ; ++i) xpa[i] = pkfma(hv, blk[7 + i], xpa[i]);
    }
    float xp[NQ];
#pragma unroll
    for (int i = 0; i < NQ; ++i) xp[i] = fmaxf(xpa[i].x + xpa[i].y, 0.0f);

    // ---- AngleEmbedding: product state. q0 factor = lane-parity select;
    // pr[16] spans q1..q4 (q_i at j-bit 4-i); q5 in the v2 components.
    float cq[NQ], sq[NQ];
#pragma unroll
    for (int q = 0; q < NQ; ++q) __sincosf(0.5f * xp[q], &sq[q], &cq[q]);

    const float g0 = podd ? sq[0] : cq[0];
    float pr[16];
    pr[0] = g0;
#pragma unroll
    for (int q = 1; q <= 4; ++q) {
        const int sz = 1 << (q - 1);
#pragma unroll
        for (int k = sz - 1; k >= 0; --k) {
            const float v = pr[k];
            pr[2 * k]     = v * cq[q];
            pr[2 * k + 1] = v * sq[q];
        }
    }
    v2 st[16];
    const v2 cs5 = mk2(cq[5], sq[5]);
#pragma unroll
    for (int j = 0; j < 16; ++j) st[j] = mk2(pr[j], pr[j]) * cs5;

    // ---- 4 layers of [CNOT ring] + [RY(qw[l,i])], constants from ws.
#pragma unroll
    for (int l = 0; l < NL; ++l) {
        const float* cst = ws + l * 16;

        // CNOT(0,1): ctrl = lane parity (q0), tgt = j-bit3 (q1).
#pragma unroll
        for (int j = 0; j < 8; ++j) {
            const v2 a = st[j], b = st[j | 8];
            st[j]     = podd ? b : a;
            st[j | 8] = podd ? a : b;
        }
        // CNOT(1,2), (2,3), (3,4): pure register renames.
#pragma unroll
        for (int j = 0; j < 16; ++j)
            if ((j & 8) && !(j & 4)) { v2 tmp = st[j]; st[j] = st[j | 4]; st[j | 4] = tmp; }
#pragma unroll
        for (int j = 0; j < 16; ++j)
            if ((j & 4) && !(j & 2)) { v2 tmp = st[j]; st[j] = st[j | 2]; st[j | 2] = tmp; }
#pragma unroll
        for (int j = 0; j < 16; ++j)
            if ((j & 2) && !(j & 1)) { v2 tmp = st[j]; st[j] = st[j | 1]; st[j | 1] = tmp; }
        // CNOT(4,5): ctrl = j-bit0 (q4), tgt = v2 component swap (rename).
#pragma unroll
        for (int j = 0; j < 16; ++j)
            if (j & 1) st[j] = __builtin_shufflevector(st[j], st[j], 1, 0);

        // CNOT(5,0) fused with RY(q0): component routing via DPP involution:
        //   new = c*(st.x, dpp(st.y)) + ssg*(dpp(st.x), st.y)
        {
            const float c0r = cst[0], s0r = cst[1];
            const float ssg = podd ? s0r : -s0r;
            const v2 c2 = mk2(c0r, c0r), sg2 = mk2(ssg, ssg);
#pragma unroll
            for (int j = 0; j < 16; ++j) {
                const float px = dppx1(st[j].x);
                const float py = dppx1(st[j].y);
                const v2 A  = mk2(st[j].x, py);
                const v2 Bv = mk2(px, st[j].y);
                st[j] = pkfma(sg2, Bv, A * c2);
            }
        }
        // RY(q1..q4): 3 packed shears per register pair (8 pairs each).
#pragma unroll
        for (int i = 1; i <= 4; ++i) {
            const int m = 1 << (4 - i);
            const v2 vnt = mk2(cst[2 * i], cst[2 * i]);          // -tan(h/2)
            const v2 vs  = mk2(cst[2 * i + 1], cst[2 * i + 1]);  // sin(h)
#pragma unroll
            for (int j = 0; j < 16; ++j) {
                if (!(j & m)) {
                    v2 a = st[j], b = st[j | m];
                    a = pkfma(vnt, b, a);
                    b = pkfma(vs, a, b);
                    a = pkfma(vnt, b, a);
                    st[j] = a; st[j | m] = b;
                }
            }
        }
        // RY(q5): intra-register scalar shears.
        {
            const float nt = cst[10], s5 = cst[11];
#pragma unroll
            for (int j = 0; j < 16; ++j) {
                float a0 = st[j].x, a1 = st[j].y;
                a0 = fmaf(nt, a1, a0);
                a1 = fmaf(s5, a0, a1);
                a0 = fmaf(nt, a1, a0);
                st[j] = mk2(a0, a1);
            }
        }
    }

    // ---- probabilities + Z expectations. Per-lane partial tree over the 32
    // local amps, then one DPP add per sum to fold in the partner half.
    float a[16];
    float S5l = 0.0f;
#pragma unroll
    for (int j = 0; j < 16; ++j) {
        const v2 pp = st[j] * st[j];
        a[j] = pp.x + pp.y;
        S5l += pp.x;
    }
    float S1l = 0.0f;
#pragma unroll
    for (int j = 0; j < 8; ++j) S1l += a[j];
    float b8[8];
#pragma unroll
    for (int j = 0; j < 8; ++j) b8[j] = a[j] + a[j | 8];
    const float S2l = b8[0] + b8[1] + b8[2] + b8[3];
    float b4[4];
#pragma unroll
    for (int j = 0; j < 4; ++j) b4[j] = b8[j] + b8[j | 4];
    const float S3l = b4[0] + b4[1];
    float b2v[2];
    b2v[0] = b4[0] + b4[2];
    b2v[1] = b4[1] + b4[3];
    const float S4l = b2v[0];
    const float Tl  = b2v[0] + b2v[1];

    const float To = dppx1(Tl);
    const float T  = Tl + To;
    const float S0 = podd ? To : Tl;           // total prob of the q0=0 lane
    const float S1 = S1l + dppx1(S1l);
    const float S2 = S2l + dppx1(S2l);
    const float S3 = S3l + dppx1(S3l);
    const float S4 = S4l + dppx1(S4l);
    const float S5 = S5l + dppx1(S5l);

    float z[NQ];
    z[0] = fmaf(2.0f, S0, -T);
    z[1] = fmaf(2.0f, S1, -T);
    z[2] = fmaf(2.0f, S2, -T);
    z[3] = fmaf(2.0f, S3, -T);
    z[4] = fmaf(2.0f, S4, -T);
    z[5] = fmaf(2.0f, S5, -T);

    // ---- heads (computed on both lanes, stored by the even lane only).
    float logits[NA];
#pragma unroll
    for (int aidx = 0; aidx < NA; ++aidx) {
        float acc = bp[aidx];
#pragma unroll
        for (int q = 0; q < NQ; ++q) acc = fmaf(z[q], Wp[aidx * NQ + q], acc);
        logits[aidx] = acc;
    }
    float m = logits[0];
#pragma unroll
    for (int aidx = 1; aidx < NA; ++aidx) m = fmaxf(m, logits[aidx]);
    float e[NA];
    float esum = 0.0f;
#pragma unroll
    for (int aidx = 0; aidx < NA; ++aidx) { e[aidx] = __expf(logits[aidx] - m); esum += e[aidx]; }
    const float inv = 1.0f / esum;

    float4 pol;
    pol.x = e[0] * inv; pol.y = e[1] * inv; pol.z = e[2] * inv; pol.w = e[3] * inv;

    float v = bv[0];
#pragma unroll
    for (int q = 0; q < NQ; ++q) v = fmaf(z[q], Wv[q], v);

    if (!podd) {
        reinterpret_cast<float4*>(out)[s] = pol;       // policy: (B,4)
        out[(size_t)B * NA + s] = v;                   // value: (B,)
    }
}

extern "C" void kernel_launch(void* const* d_in, const int* in_sizes, int n_in,
                              void* d_out, int out_size, void* d_ws, size_t ws_size,
                              hipStream_t stream) {
    const float* x  = (const float*)d_in[0];
    const float* W1 = (const float*)d_in[1];
    const float* b1 = (const float*)d_in[2];
    const float* W2 = (const float*)d_in[3];
    const float* b2 = (const float*)d_in[4];
    const float* qw = (const float*)d_in[5];
    const float* Wp = (const float*)d_in[6];
    const float* bp = (const float*)d_in[7];
    const float* Wv = (const float*)d_in[8];
    const float* bv = (const float*)d_in[9];
    float* out = (float*)d_out;
    float* ws  = (float*)d_ws;   // needs 1088 floats = 4352 B

    const int B = in_sizes[0] / NQ;      // 262144

    hipLaunchKernelGGL(qprep_kernel, dim3(1), dim3(256), 0, stream,
                       W1, b1, W2, qw, ws);

    dim3 block(256);
    dim3 grid((2 * B + 255) / 256);      // two lanes per sample
    hipLaunchKernelGGL(qpolicy_kernel, grid, block, 0, stream,
                       x, b2, Wp, bp, Wv, bv, ws, out, B);
}

// Round 4
// 101.826 us; speedup vs baseline: 1.3441x; 1.0435x over previous
//
#include <hip/hip_runtime.h>
#include <math.h>

// QuantumPolicy: MLP(6->64->6) -> 6-qubit RY/CNOT circuit (4 layers) -> Z exp
// -> softmax policy head (4) + value head (1).
//
// Pipeline (one stream, graph-safe, ordered by stream dependency):
//   1) mlp_kernel   (B threads): per-sample xp = relu(relu(x@W1^T+b1)@W2^T+b2)
//      written to ws; block 0 also writes the 4x16 layer-constant table
//      (range-reduced shear form). This removes the REDUNDANT per-lane-pair
//      MLP (~27% of the main kernel's instructions) -- the MLP is now paid
//      once per sample instead of twice, in a ~3 us kernel.
//   2) qpolicy_kernel (2B threads): LANE-SPLIT circuit. Qubit 0 = lane parity
//      (DPP quad pairs), qubits 1..4 = register index bits, qubit 5 = v2
//      component; 16 x float2 per lane, 8 waves/SIMD resident.
//
// Round-4 trims vs round 3:
//  - MLP hoisted out (above); xp read back as 3 x v2 (L2-resident, ~6.3 MB).
//  - Layer-1 CNOT(0,1) folded into the embedding tree: for odd lanes the
//    conditional [0..7]<->[8..15] swap of a PRODUCT state == swapping (c1,s1)
//    in the tree's first level -> 2 cndmask replace 32 (bit-exact).
//  - s_sleep stagger removed (all blocks exactly resident; stagger only
//    delayed the tail).
//
// ws layout (floats): [0..63] layer consts (16/layer: c0,s0,nt1,s1..nt5,s5),
//                     [256 ..] xp array, 6 floats per sample (6.3 MB).

#define NQ 6
#define NL 4
#define NA 4
#define PD 64

typedef float v2 __attribute__((ext_vector_type(2)));

__device__ __forceinline__ v2 mk2(float a, float b) { v2 r; r.x = a; r.y = b; return r; }
__device__ __forceinline__ v2 pkfma(v2 a, v2 b, v2 c) { return __builtin_elementwise_fma(a, b, c); }

// Swap with DPP-quad neighbor (lane ^ 1). Full-rate VALU, exec all-on.
__device__ __forceinline__ float dppx1(float v) {
    int i = __builtin_bit_cast(int, v);
    i = __builtin_amdgcn_mov_dpp(i, 0xB1, 0xF, 0xF, true); // quad_perm [1,0,3,2]
    return __builtin_bit_cast(float, i);
}

// ---- kernel 1: per-sample MLP (+ layer-constant prep on block 0).
__global__ __launch_bounds__(256) void mlp_kernel(
    const float* __restrict__ x,
    const float* __restrict__ W1,
    const float* __restrict__ b1,
    const float* __restrict__ W2,
    const float* __restrict__ b2,
    const float* __restrict__ qw,
    float* __restrict__ ws,
    int B)
{
    const int s = blockIdx.x * blockDim.x + threadIdx.x;

    // layer rotation constants (once, block 0)
    if (blockIdx.x == 0 && threadIdx.x < NL * NQ) {
        const int l = threadIdx.x / NQ, i = threadIdx.x % NQ;
        const float hh0 = 0.5f * qw[l * NQ + i];
        float* dst = ws + l * 16;
        if (i == 0) {
            dst[0] = cosf(hh0);
            dst[1] = sinf(hh0);
        } else {
            // range-reduce into (-pi/2, pi/2]; global sign killed by squaring
            const float hh = (hh0 > 1.5707963f) ? (hh0 - 3.14159265358979f) : hh0;
            const float sh = sinf(hh), ch = cosf(hh);
            dst[2 * i]     = -sh / (1.0f + ch);   // -tan(h/2), |t| <= 1
            dst[2 * i + 1] = sh;
        }
    }
    if (s >= B) return;

    const v2* xv = reinterpret_cast<const v2*>(x + (size_t)s * NQ);
    const v2 x01 = xv[0], x23 = xv[1], x45 = xv[2];

    const v2* W1v = reinterpret_cast<const v2*>(W1);  // rows of 6 = 3 v2
    const v2* W2v = reinterpret_cast<const v2*>(W2);  // rows of 64 = 32 v2

    v2 xpa[NQ];
#pragma unroll
    for (int i = 0; i < NQ; ++i) xpa[i] = mk2(b2[i], 0.0f);
#pragma unroll
    for (int k2 = 0; k2 < PD / 2; ++k2) {
        float hu[2];
#pragma unroll
        for (int u = 0; u < 2; ++u) {
            const int j = 2 * k2 + u;
            v2 acc = mk2(b1[j], 0.0f);
            acc = pkfma(x01, W1v[j * 3 + 0], acc);
            acc = pkfma(x23, W1v[j * 3 + 1], acc);
            acc = pkfma(x45, W1v[j * 3 + 2], acc);
            hu[u] = fmaxf(acc.x + acc.y, 0.0f);
        }
        const v2 hv = mk2(hu[0], hu[1]);
#pragma unroll
        for (int i = 0; i < NQ; ++i)
            xpa[i] = pkfma(hv, W2v[i * (PD / 2) + k2], xpa[i]);
    }

    v2* xpo = reinterpret_cast<v2*>(ws + 256) + (size_t)s * 3;
#pragma unroll
    for (int i = 0; i < 3; ++i)
        xpo[i] = mk2(fmaxf(xpa[2 * i].x     + xpa[2 * i].y,     0.0f),
                     fmaxf(xpa[2 * i + 1].x + xpa[2 * i + 1].y, 0.0f));
}

// ---- kernel 2: circuit + heads, lane-split.
__global__ __launch_bounds__(256) void qpolicy_kernel(
    const float* __restrict__ ws,
    const float* __restrict__ Wp,
    const float* __restrict__ bp,
    const float* __restrict__ Wv,
    const float* __restrict__ bv,
    float* __restrict__ out,
    int B)
{
    const int t = blockIdx.x * blockDim.x + threadIdx.x; // 0 .. 2B-1
    const int s = t >> 1;                                // sample index
    const bool podd = (t & 1) != 0;                      // q0 value of this lane

    // ---- load xp[s, 0:6] (pair lanes share 24 B; L1 broadcast, L2-resident)
    const v2* xpv = reinterpret_cast<const v2*>(ws + 256) + (size_t)s * 3;
    const v2 p01 = xpv[0], p23 = xpv[1], p45 = xpv[2];
    const float xp[NQ] = { p01.x, p01.y, p23.x, p23.y, p45.x, p45.y };

    // ---- AngleEmbedding: product state. q0 factor = lane-parity select;
    // pr[16] spans q1..q4 (q_i at j-bit 4-i); q5 in the v2 components.
    float cq[NQ], sq[NQ];
#pragma unroll
    for (int q = 0; q < NQ; ++q) __sincosf(0.5f * xp[q], &sq[q], &cq[q]);

    // Fold layer-1 CNOT(0,1): on odd lanes (q0=1) the conditional swap of a
    // product state's [0..7]<->[8..15] halves == swapping (c1,s1) here.
    {
        const float c1 = podd ? sq[1] : cq[1];
        const float s1 = podd ? cq[1] : sq[1];
        cq[1] = c1; sq[1] = s1;
    }

    const float g0 = podd ? sq[0] : cq[0];
    float pr[16];
    pr[0] = g0;
#pragma unroll
    for (int q = 1; q <= 4; ++q) {
        const int sz = 1 << (q - 1);
#pragma unroll
        for (int k = sz - 1; k >= 0; --k) {
            const float v = pr[k];
            pr[2 * k]     = v * cq[q];
            pr[2 * k + 1] = v * sq[q];
        }
    }
    v2 st[16];
    const v2 cs5 = mk2(cq[5], sq[5]);
#pragma unroll
    for (int j = 0; j < 16; ++j) st[j] = mk2(pr[j], pr[j]) * cs5;

    // ---- 4 layers of [CNOT ring] + [RY(qw[l,i])], constants from ws.
#pragma unroll
    for (int l = 0; l < NL; ++l) {
        const float* cst = ws + l * 16;

        // CNOT(0,1): ctrl = lane parity (q0), tgt = j-bit3 (q1).
        // (layer 1's instance folded into the embedding tree above)
        if (l > 0) {
#pragma unroll
            for (int j = 0; j < 8; ++j) {
                const v2 a = st[j], b = st[j | 8];
                st[j]     = podd ? b : a;
                st[j | 8] = podd ? a : b;
            }
        }
        // CNOT(1,2), (2,3), (3,4): pure register renames.
#pragma unroll
        for (int j = 0; j < 16; ++j)
            if ((j & 8) && !(j & 4)) { v2 tmp = st[j]; st[j] = st[j | 4]; st[j | 4] = tmp; }
#pragma unroll
        for (int j = 0; j < 16; ++j)
            if ((j & 4) && !(j & 2)) { v2 tmp = st[j]; st[j] = st[j | 2]; st[j | 2] = tmp; }
#pragma unroll
        for (int j = 0; j < 16; ++j)
            if ((j & 2) && !(j & 1)) { v2 tmp = st[j]; st[j] = st[j | 2 - 1]; st[j | 1] = tmp; }
        // CNOT(4,5): ctrl = j-bit0 (q4), tgt = v2 component swap (rename).
#pragma unroll
        for (int j = 0; j < 16; ++j)
            if (j & 1) st[j] = __builtin_shufflevector(st[j], st[j], 1, 0);

        // CNOT(5,0) fused with RY(q0): component routing via DPP involution:
        //   new = c*(st.x, dpp(st.y)) + ssg*(dpp(st.x), st.y)
        {
            const float c0r = cst[0], s0r = cst[1];
            const float ssg = podd ? s0r : -s0r;
            const v2 c2 = mk2(c0r, c0r), sg2 = mk2(ssg, ssg);
#pragma unroll
            for (int j = 0; j < 16; ++j) {
                const float px = dppx1(st[j].x);
                const float py = dppx1(st[j].y);
                const v2 A  = mk2(st[j].x, py);
                const v2 Bv = mk2(px, st[j].y);
                st[j] = pkfma(sg2, Bv, A * c2);
            }
        }
        // RY(q1..q4): 3 packed shears per register pair (8 pairs each).
#pragma unroll
        for (int i = 1; i <= 4; ++i) {
            const int m = 1 << (4 - i);
            const v2 vnt = mk2(cst[2 * i], cst[2 * i]);          // -tan(h/2)
            const v2 vs  = mk2(cst[2 * i + 1], cst[2 * i + 1]);  // sin(h)
#pragma unroll
            for (int j = 0; j < 16; ++j) {
                if (!(j & m)) {
                    v2 a = st[j], b = st[j | m];
                    a = pkfma(vnt, b, a);
                    b = pkfma(vs, a, b);
                    a = pkfma(vnt, b, a);
                    st[j] = a; st[j | m] = b;
                }
            }
        }
        // RY(q5): intra-register scalar shears.
        {
            const float nt = cst[10], s5 = cst[11];
#pragma unroll
            for (int j = 0; j < 16; ++j) {
                float a0 = st[j].x, a1 = st[j].y;
                a0 = fmaf(nt, a1, a0);
                a1 = fmaf(s5, a0, a1);
                a0 = fmaf(nt, a1, a0);
                st[j] = mk2(a0, a1);
            }
        }
    }

    // ---- probabilities + Z expectations. Per-lane partial tree over the 32
    // local amps, then one DPP add per sum to fold in the partner half.
    float a[16];
    float S5l = 0.0f;
#pragma unroll
    for (int j = 0; j < 16; ++j) {
        const v2 pp = st[j] * st[j];
        a[j] = pp.x + pp.y;
        S5l += pp.x;
    }
    float S1l = 0.0f;
#pragma unroll
    for (int j = 0; j < 8; ++j) S1l += a[j];
    float b8[8];
#pragma unroll
    for (int j = 0; j < 8; ++j) b8[j] = a[j] + a[j | 8];
    const float S2l = b8[0] + b8[1] + b8[2] + b8[3];
    float b4[4];
#pragma unroll
    for (int j = 0; j < 4; ++j) b4[j] = b8[j] + b8[j | 4];
    const float S3l = b4[0] + b4[1];
    float b2v[2];
    b2v[0] = b4[0] + b4[2];
    b2v[1] = b4[1] + b4[3];
    const float S4l = b2v[0];
    const float Tl  = b2v[0] + b2v[1];

    const float To = dppx1(Tl);
    const float T  = Tl + To;
    const float S0 = podd ? To : Tl;           // total prob of the q0=0 lane
    const float S1 = S1l + dppx1(S1l);
    const float S2 = S2l + dppx1(S2l);
    const float S3 = S3l + dppx1(S3l);
    const float S4 = S4l + dppx1(S4l);
    const float S5 = S5l + dppx1(S5l);

    float z[NQ];
    z[0] = fmaf(2.0f, S0, -T);
    z[1] = fmaf(2.0f, S1, -T);
    z[2] = fmaf(2.0f, S2, -T);
    z[3] = fmaf(2.0f, S3, -T);
    z[4] = fmaf(2.0f, S4, -T);
    z[5] = fmaf(2.0f, S5, -T);

    // ---- heads (computed on both lanes, stored by the even lane only).
    float logits[NA];
#pragma unroll
    for (int aidx = 0; aidx < NA; ++aidx) {
        float acc = bp[aidx];
#pragma unroll
        for (int q = 0; q < NQ; ++q) acc = fmaf(z[q], Wp[aidx * NQ + q], acc);
        logits[aidx] = acc;
    }
    float m = logits[0];
#pragma unroll
    for (int aidx = 1; aidx < NA; ++aidx) m = fmaxf(m, logits[aidx]);
    float e[NA];
    float esum = 0.0f;
#pragma unroll
    for (int aidx = 0; aidx < NA; ++aidx) { e[aidx] = __expf(logits[aidx] - m); esum += e[aidx]; }
    const float inv = 1.0f / esum;

    float4 pol;
    pol.x = e[0] * inv; pol.y = e[1] * inv; pol.z = e[2] * inv; pol.w = e[3] * inv;

    float v = bv[0];
#pragma unroll
    for (int q = 0; q < NQ; ++q) v = fmaf(z[q], Wv[q], v);

    if (!podd) {
        reinterpret_cast<float4*>(out)[s] = pol;       // policy: (B,4)
        out[(size_t)B * NA + s] = v;                   // value: (B,)
    }
}

extern "C" void kernel_launch(void* const* d_in, const int* in_sizes, int n_in,
                              void* d_out, int out_size, void* d_ws, size_t ws_size,
                              hipStream_t stream) {
    const float* x  = (const float*)d_in[0];
    const float* W1 = (const float*)d_in[1];
    const float* b1 = (const float*)d_in[2];
    const float* W2 = (const float*)d_in[3];
    const float* b2 = (const float*)d_in[4];
    const float* qw = (const float*)d_in[5];
    const float* Wp = (const float*)d_in[6];
    const float* bp = (const float*)d_in[7];
    const float* Wv = (const float*)d_in[8];
    const float* bv = (const float*)d_in[9];
    float* out = (float*)d_out;
    float* ws  = (float*)d_ws;   // needs 256 + 6*B floats (~6.3 MB)

    const int B = in_sizes[0] / NQ;      // 262144

    hipLaunchKernelGGL(mlp_kernel, dim3((B + 255) / 256), dim3(256), 0, stream,
                       x, W1, b1, W2, b2, qw, ws, B);

    hipLaunchKernelGGL(qpolicy_kernel, dim3((2 * B + 255) / 256), dim3(256), 0, stream,
                       ws, Wp, bp, Wv, bv, out, B);
}